// Round 3
// baseline (1413.103 us; speedup 1.0000x reference)
//
#include <hip/hip_runtime.h>
#include <math.h>

#define BB 8
#define NN 2000
#define FIN 128
#define HH 4
#define FO 64
#define CC 256  // HH*FO

typedef short bf16x8 __attribute__((ext_vector_type(8)));
typedef float f32x4 __attribute__((ext_vector_type(4)));
typedef unsigned long long u64;

__device__ __forceinline__ unsigned short f2bf(float v) {
    union { float f; unsigned u; } x;
    x.f = v;
    unsigned r = x.u + 0x7fffu + ((x.u >> 16) & 1u);  // RNE
    return (unsigned short)(r >> 16);
}

// ---------------------------------------------------------------------------
// K1: h = x @ W.  rows = B*N = 16000, K = 128, cols = 256.
// ---------------------------------------------------------------------------
__global__ __launch_bounds__(256) void k_gemm_xw(const float* __restrict__ x,
                                                 const float* __restrict__ W,
                                                 float* __restrict__ hfeat) {
    __shared__ float xs[16 * FIN];
    const int row0 = blockIdx.x * 16;
    const int t = threadIdx.x;
    for (int k = t; k < 16 * FIN; k += 256) xs[k] = x[row0 * FIN + k];
    __syncthreads();
    const int c = t;
    float acc[16];
#pragma unroll
    for (int r = 0; r < 16; ++r) acc[r] = 0.f;
#pragma unroll 2
    for (int k = 0; k < FIN; k += 4) {
        const float w0 = W[(k + 0) * CC + c];
        const float w1 = W[(k + 1) * CC + c];
        const float w2 = W[(k + 2) * CC + c];
        const float w3 = W[(k + 3) * CC + c];
#pragma unroll
        for (int r = 0; r < 16; ++r) {
            const float4 xv = *(const float4*)(xs + r * FIN + k);
            acc[r] = fmaf(xv.x, w0, fmaf(xv.y, w1, fmaf(xv.z, w2, fmaf(xv.w, w3, acc[r]))));
        }
    }
#pragma unroll
    for (int r = 0; r < 16; ++r) hfeat[(row0 + r) * CC + c] = acc[r];
}

// ---------------------------------------------------------------------------
// K1b: adjacency bitmask.  adjb[i][w] bit l = (adj[i][w*64+l] != 0).
// Rows padded to 2048 bits (32 u64 words); pad bits are 0.
// NOTE: adjb lives in alpha scratch -> k_alpha (runs last, overwrites alpha)
// must read the ORIGINAL adj input instead.
// ---------------------------------------------------------------------------
__global__ __launch_bounds__(256) void k_adjbits(const int* __restrict__ adj,
                                                 u64* __restrict__ adjb) {
    const int w = blockIdx.x * 4 + (threadIdx.x >> 6);  // [0, 64000)
    const int lane = threadIdx.x & 63;
    const int i = w >> 5, wd = w & 31;
    const int j = wd * 64 + lane;
    int av = 0;
    if (j < NN) av = adj[(size_t)i * NN + j];
    const u64 mask = __ballot(av != 0);
    if (lane == 0) adjb[(size_t)i * 32 + wd] = mask;
}

// ---------------------------------------------------------------------------
// K2: e_src[b][h][n] = h·a_src, e_dst = h·a_dst.  Wave per (b,n,h).
// ---------------------------------------------------------------------------
__global__ __launch_bounds__(256) void k_calc_e(const float* __restrict__ hfeat,
                                                const float* __restrict__ a,
                                                float* __restrict__ e_src,
                                                float* __restrict__ e_dst) {
    const int widx = blockIdx.x * 4 + (threadIdx.x >> 6);
    const int lane = threadIdx.x & 63;
    const int b = widx / (NN * HH);
    const int rem = widx - b * (NN * HH);
    const int n = rem / HH;
    const int h = rem - n * HH;
    const float hv = hfeat[((b * NN + n) * HH + h) * FO + lane];
    float p1 = hv * a[h * 2 * FO + lane];
    float p2 = hv * a[h * 2 * FO + FO + lane];
#pragma unroll
    for (int off = 32; off > 0; off >>= 1) {
        p1 += __shfl_xor(p1, off);
        p2 += __shfl_xor(p2, off);
    }
    if (lane == 0) {
        e_src[(b * HH + h) * NN + n] = p1;
        e_dst[(b * HH + h) * NN + n] = p2;
    }
}

// ---------------------------------------------------------------------------
// K3: softmax stats, float4 x 4-j per lane per iter.  Per 4-j tile: local
// max + partial sum (4 exp), then ONE online merge (2 exp) -> ~6 exp / 4j
// vs 8 before, and 8 loop iters instead of 32.  Masked tiles contribute
// l4 = 4 at m4 = -1e30, which the merge multiplies by exp(-1e30 - m) = 0.
// ---------------------------------------------------------------------------
__global__ __launch_bounds__(256) void k_softmax_ml(const u64* __restrict__ adjb,
                                                    const float* __restrict__ e_src,
                                                    const float* __restrict__ e_dst,
                                                    float* __restrict__ mArr,
                                                    float* __restrict__ rlArr) {
    const int widx = blockIdx.x * 4 + (threadIdx.x >> 6);  // [0, B*N*H)
    const int lane = threadIdx.x & 63;
    const int b = widx / (NN * HH);
    const int rem = widx - b * (NN * HH);
    const int i = rem / HH;
    const int h = rem - i * HH;
    const float* ed = e_dst + (b * HH + h) * NN;
    const u64* ab = adjb + (size_t)i * 32;
    const float ei = e_src[(b * HH + h) * NN + i];
    float m = -1e30f, l = 0.f;
#pragma unroll 2
    for (int it = 0; it < 8; ++it) {
        const int j = it * 256 + lane * 4;          // 0..2044; OOB j masked by pad bits
        const u64 wbits = ab[j >> 6];
        const unsigned nib = (unsigned)((wbits >> (j & 63)) & 0xFull);
        const float4 ev = *(const float4*)(ed + j);  // OOB reads stay inside ws; masked
        float s0 = ei + ev.x; s0 = s0 > 0.f ? s0 : 0.2f * s0; s0 = (nib & 1u) ? s0 : -1e30f;
        float s1 = ei + ev.y; s1 = s1 > 0.f ? s1 : 0.2f * s1; s1 = (nib & 2u) ? s1 : -1e30f;
        float s2 = ei + ev.z; s2 = s2 > 0.f ? s2 : 0.2f * s2; s2 = (nib & 4u) ? s2 : -1e30f;
        float s3 = ei + ev.w; s3 = s3 > 0.f ? s3 : 0.2f * s3; s3 = (nib & 8u) ? s3 : -1e30f;
        const float m4 = fmaxf(fmaxf(s0, s1), fmaxf(s2, s3));
        const float l4 = __expf(s0 - m4) + __expf(s1 - m4) + __expf(s2 - m4) + __expf(s3 - m4);
        const float nm = fmaxf(m, m4);
        l = l * __expf(m - nm) + l4 * __expf(m4 - nm);
        m = nm;
    }
#pragma unroll
    for (int off = 32; off > 0; off >>= 1) {
        const float mo = __shfl_xor(m, off);
        const float lo = __shfl_xor(l, off);
        const float mn = fmaxf(m, mo);
        l = l * __expf(m - mn) + lo * __expf(mo - mn);
        m = mn;
    }
    if (lane == 0) {
        mArr[(b * HH + h) * NN + i] = m;
        rlArr[(b * HH + h) * NN + i] = 1.f / l;
    }
}

// ---------------------------------------------------------------------------
// K3b: hT in MFMA-FRAGMENT ORDER: hT[bh][s][ft][quad][l16][e] (shorts),
// s = k-step of 32 j (64 steps, j padded to 2048), ft = f>>4, l16 = f&15,
// quad = (j>>3)&3, e = j&7.  Consumer A-load = base + s*2048 + ft*512 +
// lane*8  -> one fully-coalesced contiguous 1KB global_load_dwordx4 per
// MFMA operand (was 16 scattered 64B segments).
// Write side: dst offset == k2 (identity) -> linear coalesced stores.
// ---------------------------------------------------------------------------
__global__ __launch_bounds__(256) void k_transpose(const float* __restrict__ hfeat,
                                                   unsigned short* __restrict__ hT) {
    __shared__ unsigned short sm[64 * 65];
    const int jt = blockIdx.x, h = blockIdx.y, b = blockIdx.z;
    const int j0 = jt * 64;
    const int t = threadIdx.x;
    for (int k = t; k < 4096; k += 256) {
        const int jj = k >> 6, f = k & 63;
        const int j = j0 + jj;
        const float v = (j < NN) ? hfeat[((b * NN + j) * HH + h) * FO + f] : 0.f;
        sm[jj * 65 + f] = f2bf(v);
    }
    __syncthreads();
    unsigned short* dst = hT + (size_t)(b * HH + h) * 131072 + (size_t)jt * 4096;
    for (int k2 = t; k2 < 4096; k2 += 256) {
        const int s_loc = k2 >> 11;          // 0..1  (two 32-j k-steps per 64-j tile)
        const int ft   = (k2 >> 9) & 3;
        const int quad = (k2 >> 7) & 3;
        const int l16  = (k2 >> 3) & 15;
        const int e    = k2 & 7;
        const int jj = s_loc * 32 + quad * 8 + e;
        const int f  = ft * 16 + l16;
        dst[k2] = sm[jj * 65 + f];           // dst offset == k2 by construction
    }
}

// ---------------------------------------------------------------------------
// K5: out partials, register-resident MFMA, fragment-ordered A loads.
// One INDEPENDENT wave per (b, h, 16-row i-tile): 4000 waves, no LDS.
//   A-load (ft,kk):  hT + bh*131072 + (2*jt+kk)*2048 + ft*512 + lane*8
//     -> contiguous 1KB per instruction, 8KB contiguous per jt.
//   B-fragment: P computed in-register from e_dst + bitmask.
//   C/D: acc[ft] = 4 consecutive f -> direct float4 store.
// ---------------------------------------------------------------------------
__global__ __launch_bounds__(256) void k_out_mfma2(const u64* __restrict__ adjb,
                                                   const unsigned short* __restrict__ hT,
                                                   const float* __restrict__ e_src,
                                                   const float* __restrict__ e_dst,
                                                   const float* __restrict__ mArr,
                                                   const float* __restrict__ rlArr,
                                                   float* __restrict__ part) {
    const int w = blockIdx.x * 4 + (threadIdx.x >> 6);  // [0, 4000)
    const int lane = threadIdx.x & 63;
    const int b = w / 500;
    const int rem = w - b * 500;
    const int h = rem / 125;
    const int it = rem - h * 125;
    const int l16 = lane & 15, quad = lane >> 4;
    const int i = it * 16 + l16;  // < 2000 always (125*16 == 2000)
    const int bh = b * HH + h;
    const float es = e_src[bh * NN + i];
    const float mm = mArr[bh * NN + i];
    const float rl = rlArr[bh * NN + i];
    const float* ed = e_dst + bh * NN;
    const u64* ab = adjb + (size_t)i * 32;
    const unsigned short* hbase = hT + (size_t)bh * 131072 + (size_t)lane * 8;

    f32x4 acc[4];
#pragma unroll
    for (int ft = 0; ft < 4; ++ft) {
        acc[ft][0] = 0.f; acc[ft][1] = 0.f; acc[ft][2] = 0.f; acc[ft][3] = 0.f;
    }

#pragma unroll 2
    for (int jt = 0; jt < 32; ++jt) {
        const int j0 = jt * 64;
        const u64 bits = ab[jt];
        const unsigned m0 = ((unsigned)(bits >> (quad * 8))) & 0xffu;
        const unsigned m1 = ((unsigned)(bits >> 32) >> (quad * 8)) & 0xffu;
        // e_dst for this lane's 2x8 j values (16-lane broadcast within quad)
        const float4 ea0 = *(const float4*)(ed + j0 + quad * 8);
        const float4 ea1 = *(const float4*)(ed + j0 + quad * 8 + 4);
        const float4 eb0 = *(const float4*)(ed + j0 + 32 + quad * 8);
        const float4 eb1 = *(const float4*)(ed + j0 + 32 + quad * 8 + 4);
        const unsigned short* hp0 = hbase + (size_t)jt * 4096;  // k-step 2*jt

        {   // kk = 0
            const float ev[8] = {ea0.x, ea0.y, ea0.z, ea0.w, ea1.x, ea1.y, ea1.z, ea1.w};
            bf16x8 bfr;
#pragma unroll
            for (int e = 0; e < 8; ++e) {
                float s = es + ev[e];
                s = s > 0.f ? s : 0.2f * s;
                float p = __expf(s - mm) * rl;
                p = ((m0 >> e) & 1u) ? p : 0.f;
                bfr[e] = (short)f2bf(p);
            }
#pragma unroll
            for (int ft = 0; ft < 4; ++ft) {
                const bf16x8 af = *(const bf16x8*)(hp0 + ft * 512);
                acc[ft] = __builtin_amdgcn_mfma_f32_16x16x32_bf16(af, bfr, acc[ft], 0, 0, 0);
            }
        }
        {   // kk = 1
            const float ev[8] = {eb0.x, eb0.y, eb0.z, eb0.w, eb1.x, eb1.y, eb1.z, eb1.w};
            bf16x8 bfr;
#pragma unroll
            for (int e = 0; e < 8; ++e) {
                float s = es + ev[e];
                s = s > 0.f ? s : 0.2f * s;
                float p = __expf(s - mm) * rl;
                p = ((m1 >> e) & 1u) ? p : 0.f;
                bfr[e] = (short)f2bf(p);
            }
#pragma unroll
            for (int ft = 0; ft < 4; ++ft) {
                const bf16x8 af = *(const bf16x8*)(hp0 + 2048 + ft * 512);
                acc[ft] = __builtin_amdgcn_mfma_f32_16x16x32_bf16(af, bfr, acc[ft], 0, 0, 0);
            }
        }
    }
    float* pp = part + (size_t)h * (BB * NN * FO) + (size_t)(b * NN + i) * FO + quad * 4;
#pragma unroll
    for (int ft = 0; ft < 4; ++ft) *(f32x4*)(pp + ft * 16) = acc[ft];
}

// ---------------------------------------------------------------------------
// K6: out = 0.25 * sum_h part[h]
// ---------------------------------------------------------------------------
__global__ __launch_bounds__(256) void k_reduce(const float* __restrict__ part,
                                                float* __restrict__ out) {
    const int idx = blockIdx.x * 256 + threadIdx.x;
    const int M = BB * NN * FO;
    out[idx] = 0.25f * (part[idx] + part[M + idx] + part[2 * M + idx] + part[3 * M + idx]);
}

// ---------------------------------------------------------------------------
// K4 (LAST): alpha write.  Reads ORIGINAL adj (L3-resident) -- adjb is in
// the region this kernel overwrites.  Nontemporal stores: the 512 MB alpha
// stream is never re-read on device, keep it out of L2.
// ---------------------------------------------------------------------------
__global__ __launch_bounds__(256) void k_alpha(const int* __restrict__ adj,
                                               const float* __restrict__ e_src,
                                               const float* __restrict__ e_dst,
                                               const float* __restrict__ mArr,
                                               const float* __restrict__ rlArr,
                                               float* __restrict__ alpha) {
    const int bi = blockIdx.x;
    const int b = bi / NN, i = bi - b * NN;
    const int t = threadIdx.x;
    float ei[HH], mm[HH], rr[HH];
#pragma unroll
    for (int h = 0; h < HH; ++h) {
        ei[h] = e_src[(b * HH + h) * NN + i];
        mm[h] = mArr[(b * HH + h) * NN + i];
        rr[h] = rlArr[(b * HH + h) * NN + i];
    }
    const float* ed = e_dst + b * HH * NN;
    const int* adjrow = adj + (size_t)i * NN;
    float* arow = alpha + (size_t)(b * NN + i) * (NN * HH);
    for (int jq = t; jq < NN / 4; jq += 256) {
        const int j0 = jq * 4;
        const int4 av4 = *(const int4*)(adjrow + j0);
        const int avs[4] = {av4.x, av4.y, av4.z, av4.w};
        float e4[HH * 4];
#pragma unroll
        for (int h = 0; h < HH; ++h) {
            const float4 v = *(const float4*)(ed + h * NN + j0);
            e4[h * 4 + 0] = v.x; e4[h * 4 + 1] = v.y; e4[h * 4 + 2] = v.z; e4[h * 4 + 3] = v.w;
        }
#pragma unroll
        for (int jj = 0; jj < 4; ++jj) {
            const bool av = avs[jj] != 0;
            float o[HH];
#pragma unroll
            for (int h = 0; h < HH; ++h) {
                float s = ei[h] + e4[h * 4 + jj];
                s = s > 0.f ? s : 0.2f * s;
                o[h] = av ? __expf(s - mm[h]) * rr[h] : 0.f;
            }
            f32x4 ov = {o[0], o[1], o[2], o[3]};
            __builtin_nontemporal_store(ov, (f32x4*)(arow + (size_t)(j0 + jj) * HH));
        }
    }
}

// ---------------------------------------------------------------------------
// Launch.  Scratch lives at the start of the alpha output region — dead until
// k_alpha, which runs LAST and reads only input/ws arrays (no scratch!).
//   alpha region layout (floats from alpha base):
//     [0,        4096000)  hfeat
//     [4096000,  8192000)  part
//     [8192000, 10289152)  hT   (bf16 fragment-order, [32 bh][64 s][2048])
//     [10289152, +128000)  adjb (u64,  [2000][32])
// ---------------------------------------------------------------------------
extern "C" void kernel_launch(void* const* d_in, const int* in_sizes, int n_in,
                              void* d_out, int out_size, void* d_ws, size_t ws_size,
                              hipStream_t stream) {
    const float* x  = (const float*)d_in[0];
    const int* adj  = (const int*)d_in[1];
    const float* W  = (const float*)d_in[2];
    const float* a  = (const float*)d_in[3];

    float* out = (float*)d_out;                         // B*N*FO floats
    float* alpha = out + (size_t)BB * NN * FO;          // B*N*N*H floats

    float* hfeat = alpha;
    float* part  = alpha + (size_t)BB * NN * CC;
    unsigned short* hT = (unsigned short*)(alpha + 2 * (size_t)BB * NN * CC);
    u64* adjb = (u64*)(alpha + 2 * (size_t)BB * NN * CC + (size_t)BB * HH * FO * 1024);

    float* ws    = (float*)d_ws;
    float* e_src = ws;
    float* e_dst = e_src + BB * HH * NN;
    float* mArr  = e_dst + BB * HH * NN;
    float* rlArr = mArr + BB * HH * NN;

    k_gemm_xw<<<1000, 256, 0, stream>>>(x, W, hfeat);
    k_adjbits<<<16000, 256, 0, stream>>>(adj, adjb);
    k_calc_e<<<16000, 256, 0, stream>>>(hfeat, a, e_src, e_dst);
    k_softmax_ml<<<16000, 256, 0, stream>>>(adjb, e_src, e_dst, mArr, rlArr);
    k_transpose<<<dim3(32, HH, BB), 256, 0, stream>>>(hfeat, hT);
    k_out_mfma2<<<1000, 256, 0, stream>>>(adjb, hT, e_src, e_dst, mArr, rlArr, part);
    k_reduce<<<4000, 256, 0, stream>>>(part, out);
    k_alpha<<<16000, 256, 0, stream>>>(adj, e_src, e_dst, mArr, rlArr, alpha);  // overwrites scratch
}

// Round 4
// 757.591 us; speedup vs baseline: 1.8653x; 1.8653x over previous
//
#include <hip/hip_runtime.h>
#include <math.h>

#define BB 8
#define NN 2000
#define FIN 128
#define HH 4
#define FO 64
#define CC 256  // HH*FO

typedef short bf16x8 __attribute__((ext_vector_type(8)));
typedef float f32x4 __attribute__((ext_vector_type(4)));
typedef unsigned long long u64;

__device__ __forceinline__ unsigned short f2bf(float v) {
    union { float f; unsigned u; } x;
    x.f = v;
    unsigned r = x.u + 0x7fffu + ((x.u >> 16) & 1u);  // RNE
    return (unsigned short)(r >> 16);
}

// ---------------------------------------------------------------------------
// K1: h = x @ W.  rows = B*N = 16000, K = 128, cols = 256.
// ---------------------------------------------------------------------------
__global__ __launch_bounds__(256) void k_gemm_xw(const float* __restrict__ x,
                                                 const float* __restrict__ W,
                                                 float* __restrict__ hfeat) {
    __shared__ float xs[16 * FIN];
    const int row0 = blockIdx.x * 16;
    const int t = threadIdx.x;
    for (int k = t; k < 16 * FIN; k += 256) xs[k] = x[row0 * FIN + k];
    __syncthreads();
    const int c = t;
    float acc[16];
#pragma unroll
    for (int r = 0; r < 16; ++r) acc[r] = 0.f;
#pragma unroll 2
    for (int k = 0; k < FIN; k += 4) {
        const float w0 = W[(k + 0) * CC + c];
        const float w1 = W[(k + 1) * CC + c];
        const float w2 = W[(k + 2) * CC + c];
        const float w3 = W[(k + 3) * CC + c];
#pragma unroll
        for (int r = 0; r < 16; ++r) {
            const float4 xv = *(const float4*)(xs + r * FIN + k);
            acc[r] = fmaf(xv.x, w0, fmaf(xv.y, w1, fmaf(xv.z, w2, fmaf(xv.w, w3, acc[r]))));
        }
    }
#pragma unroll
    for (int r = 0; r < 16; ++r) hfeat[(row0 + r) * CC + c] = acc[r];
}

// ---------------------------------------------------------------------------
// K1b: adjacency bitmask.  adjb[i][w] bit l = (adj[i][w*64+l] != 0).
// Rows padded to 2048 bits (32 u64 words); pad bits are 0.
// NOTE: adjb lives in alpha scratch -> k_alpha (runs last, overwrites alpha)
// must read the ORIGINAL adj input instead.
// ---------------------------------------------------------------------------
__global__ __launch_bounds__(256) void k_adjbits(const int* __restrict__ adj,
                                                 u64* __restrict__ adjb) {
    const int w = blockIdx.x * 4 + (threadIdx.x >> 6);  // [0, 64000)
    const int lane = threadIdx.x & 63;
    const int i = w >> 5, wd = w & 31;
    const int j = wd * 64 + lane;
    int av = 0;
    if (j < NN) av = adj[(size_t)i * NN + j];
    const u64 mask = __ballot(av != 0);
    if (lane == 0) adjb[(size_t)i * 32 + wd] = mask;
}

// ---------------------------------------------------------------------------
// K2: e_src[b][h][n] = h·a_src, e_dst = h·a_dst.  Wave per (b,n,h).
// ---------------------------------------------------------------------------
__global__ __launch_bounds__(256) void k_calc_e(const float* __restrict__ hfeat,
                                                const float* __restrict__ a,
                                                float* __restrict__ e_src,
                                                float* __restrict__ e_dst) {
    const int widx = blockIdx.x * 4 + (threadIdx.x >> 6);
    const int lane = threadIdx.x & 63;
    const int b = widx / (NN * HH);
    const int rem = widx - b * (NN * HH);
    const int n = rem / HH;
    const int h = rem - n * HH;
    const float hv = hfeat[((b * NN + n) * HH + h) * FO + lane];
    float p1 = hv * a[h * 2 * FO + lane];
    float p2 = hv * a[h * 2 * FO + FO + lane];
#pragma unroll
    for (int off = 32; off > 0; off >>= 1) {
        p1 += __shfl_xor(p1, off);
        p2 += __shfl_xor(p2, off);
    }
    if (lane == 0) {
        e_src[(b * HH + h) * NN + n] = p1;
        e_dst[(b * HH + h) * NN + n] = p2;
    }
}

// ---------------------------------------------------------------------------
// K3: softmax stats, float4 x 4-j per lane per iter.  Per 4-j tile: local
// max + partial sum (4 exp), then ONE online merge (2 exp).  Masked tiles
// contribute l4 = 4 at m4 = -1e30 -> zeroed by the merge.
// ---------------------------------------------------------------------------
__global__ __launch_bounds__(256) void k_softmax_ml(const u64* __restrict__ adjb,
                                                    const float* __restrict__ e_src,
                                                    const float* __restrict__ e_dst,
                                                    float* __restrict__ mArr,
                                                    float* __restrict__ rlArr) {
    const int widx = blockIdx.x * 4 + (threadIdx.x >> 6);  // [0, B*N*H)
    const int lane = threadIdx.x & 63;
    const int b = widx / (NN * HH);
    const int rem = widx - b * (NN * HH);
    const int i = rem / HH;
    const int h = rem - i * HH;
    const float* ed = e_dst + (b * HH + h) * NN;
    const u64* ab = adjb + (size_t)i * 32;
    const float ei = e_src[(b * HH + h) * NN + i];
    float m = -1e30f, l = 0.f;
#pragma unroll 2
    for (int it = 0; it < 8; ++it) {
        const int j = it * 256 + lane * 4;          // 0..2044; OOB j masked by pad bits
        const u64 wbits = ab[j >> 6];
        const unsigned nib = (unsigned)((wbits >> (j & 63)) & 0xFull);
        const float4 ev = *(const float4*)(ed + j);  // OOB reads stay inside ws; masked
        float s0 = ei + ev.x; s0 = s0 > 0.f ? s0 : 0.2f * s0; s0 = (nib & 1u) ? s0 : -1e30f;
        float s1 = ei + ev.y; s1 = s1 > 0.f ? s1 : 0.2f * s1; s1 = (nib & 2u) ? s1 : -1e30f;
        float s2 = ei + ev.z; s2 = s2 > 0.f ? s2 : 0.2f * s2; s2 = (nib & 4u) ? s2 : -1e30f;
        float s3 = ei + ev.w; s3 = s3 > 0.f ? s3 : 0.2f * s3; s3 = (nib & 8u) ? s3 : -1e30f;
        const float m4 = fmaxf(fmaxf(s0, s1), fmaxf(s2, s3));
        const float l4 = __expf(s0 - m4) + __expf(s1 - m4) + __expf(s2 - m4) + __expf(s3 - m4);
        const float nm = fmaxf(m, m4);
        l = l * __expf(m - nm) + l4 * __expf(m4 - nm);
        m = nm;
    }
#pragma unroll
    for (int off = 32; off > 0; off >>= 1) {
        const float mo = __shfl_xor(m, off);
        const float lo = __shfl_xor(l, off);
        const float mn = fmaxf(m, mo);
        l = l * __expf(m - mn) + lo * __expf(mo - mn);
        m = mn;
    }
    if (lane == 0) {
        mArr[(b * HH + h) * NN + i] = m;
        rlArr[(b * HH + h) * NN + i] = 1.f / l;
    }
}

// ---------------------------------------------------------------------------
// K3b: hT in MFMA-FRAGMENT ORDER: hT[bh][s][ft][quad][l16][e] (shorts).
// Consumer A-load = base + s*2048 + ft*512 + lane*8 -> contiguous 1KB per
// instruction.  Write side: dst offset == k2 (identity), linear stores.
// ---------------------------------------------------------------------------
__global__ __launch_bounds__(256) void k_transpose(const float* __restrict__ hfeat,
                                                   unsigned short* __restrict__ hT) {
    __shared__ unsigned short sm[64 * 65];
    const int jt = blockIdx.x, h = blockIdx.y, b = blockIdx.z;
    const int j0 = jt * 64;
    const int t = threadIdx.x;
    for (int k = t; k < 4096; k += 256) {
        const int jj = k >> 6, f = k & 63;
        const int j = j0 + jj;
        const float v = (j < NN) ? hfeat[((b * NN + j) * HH + h) * FO + f] : 0.f;
        sm[jj * 65 + f] = f2bf(v);
    }
    __syncthreads();
    unsigned short* dst = hT + (size_t)(b * HH + h) * 131072 + (size_t)jt * 4096;
    for (int k2 = t; k2 < 4096; k2 += 256) {
        const int s_loc = k2 >> 11;          // 0..1  (two 32-j k-steps per 64-j tile)
        const int ft   = (k2 >> 9) & 3;
        const int quad = (k2 >> 7) & 3;
        const int l16  = (k2 >> 3) & 15;
        const int e    = k2 & 7;
        const int jj = s_loc * 32 + quad * 8 + e;
        const int f  = ft * 16 + l16;
        dst[k2] = sm[jj * 65 + f];           // dst offset == k2 by construction
    }
}

// ---------------------------------------------------------------------------
// K5: fused out kernel.  Block per (b, 16-row i-tile); wave = head.
// Register-resident MFMA (fragment-ordered A loads, in-register P), then
// cross-wave h-reduction through LDS and a direct write of out -- the
// `part` buffer and k_reduce are gone (saves 256 MB of HBM round-trip).
// ---------------------------------------------------------------------------
__global__ __launch_bounds__(256) void k_out_mfma3(const u64* __restrict__ adjb,
                                                   const unsigned short* __restrict__ hT,
                                                   const float* __restrict__ e_src,
                                                   const float* __restrict__ e_dst,
                                                   const float* __restrict__ mArr,
                                                   const float* __restrict__ rlArr,
                                                   float* __restrict__ out) {
    __shared__ float red[HH][16][72];  // pitch 72 floats: 16B-aligned rows, low conflicts
    const int blk = blockIdx.x;        // [0, 1000)
    const int b = blk / 125;
    const int it = blk - b * 125;
    const int h = threadIdx.x >> 6;    // wave index = head
    const int lane = threadIdx.x & 63;
    const int l16 = lane & 15, quad = lane >> 4;
    const int i = it * 16 + l16;       // < 2000 always (125*16 == 2000)
    const int bh = b * HH + h;
    const float es = e_src[bh * NN + i];
    const float mm = mArr[bh * NN + i];
    const float rl = rlArr[bh * NN + i];
    const float* ed = e_dst + bh * NN;
    const u64* ab = adjb + (size_t)i * 32;
    const unsigned short* hbase = hT + (size_t)bh * 131072 + (size_t)lane * 8;

    f32x4 acc[4];
#pragma unroll
    for (int ft = 0; ft < 4; ++ft) {
        acc[ft][0] = 0.f; acc[ft][1] = 0.f; acc[ft][2] = 0.f; acc[ft][3] = 0.f;
    }

#pragma unroll 2
    for (int jt = 0; jt < 32; ++jt) {
        const int j0 = jt * 64;
        const u64 bits = ab[jt];
        const unsigned m0 = ((unsigned)(bits >> (quad * 8))) & 0xffu;
        const unsigned m1 = ((unsigned)(bits >> 32) >> (quad * 8)) & 0xffu;
        const float4 ea0 = *(const float4*)(ed + j0 + quad * 8);
        const float4 ea1 = *(const float4*)(ed + j0 + quad * 8 + 4);
        const float4 eb0 = *(const float4*)(ed + j0 + 32 + quad * 8);
        const float4 eb1 = *(const float4*)(ed + j0 + 32 + quad * 8 + 4);
        const unsigned short* hp0 = hbase + (size_t)jt * 4096;  // k-step 2*jt

        {   // kk = 0
            const float ev[8] = {ea0.x, ea0.y, ea0.z, ea0.w, ea1.x, ea1.y, ea1.z, ea1.w};
            bf16x8 bfr;
#pragma unroll
            for (int e = 0; e < 8; ++e) {
                float s = es + ev[e];
                s = s > 0.f ? s : 0.2f * s;
                float p = __expf(s - mm) * rl;
                p = ((m0 >> e) & 1u) ? p : 0.f;
                bfr[e] = (short)f2bf(p);
            }
#pragma unroll
            for (int ft = 0; ft < 4; ++ft) {
                const bf16x8 af = *(const bf16x8*)(hp0 + ft * 512);
                acc[ft] = __builtin_amdgcn_mfma_f32_16x16x32_bf16(af, bfr, acc[ft], 0, 0, 0);
            }
        }
        {   // kk = 1
            const float ev[8] = {eb0.x, eb0.y, eb0.z, eb0.w, eb1.x, eb1.y, eb1.z, eb1.w};
            bf16x8 bfr;
#pragma unroll
            for (int e = 0; e < 8; ++e) {
                float s = es + ev[e];
                s = s > 0.f ? s : 0.2f * s;
                float p = __expf(s - mm) * rl;
                p = ((m1 >> e) & 1u) ? p : 0.f;
                bfr[e] = (short)f2bf(p);
            }
#pragma unroll
            for (int ft = 0; ft < 4; ++ft) {
                const bf16x8 af = *(const bf16x8*)(hp0 + 2048 + ft * 512);
                acc[ft] = __builtin_amdgcn_mfma_f32_16x16x32_bf16(af, bfr, acc[ft], 0, 0, 0);
            }
        }
    }
    // cross-wave (head) reduction: stage each wave's 16x64 tile in LDS
#pragma unroll
    for (int ft = 0; ft < 4; ++ft)
        *(f32x4*)(&red[h][l16][ft * 16 + quad * 4]) = acc[ft];
    __syncthreads();
    const int t = threadIdx.x;
    const int ii = t >> 4, f4 = (t & 15) * 4;
    const int gi = it * 16 + ii;
    const f32x4 s0 = *(const f32x4*)(&red[0][ii][f4]);
    const f32x4 s1 = *(const f32x4*)(&red[1][ii][f4]);
    const f32x4 s2 = *(const f32x4*)(&red[2][ii][f4]);
    const f32x4 s3 = *(const f32x4*)(&red[3][ii][f4]);
    f32x4 o;
#pragma unroll
    for (int r = 0; r < 4; ++r) o[r] = 0.25f * (s0[r] + s1[r] + s2[r] + s3[r]);
    *(f32x4*)(out + (size_t)(b * NN + gi) * FO + f4) = o;
}

// ---------------------------------------------------------------------------
// K4 (LAST): alpha write.  Reads ORIGINAL adj (L3-resident) -- adjb is in
// the region this kernel overwrites.  PLAIN float4 stores: nontemporal
// regressed 6x (partial-line eviction -> 2.7x write amplification, R3).
// ---------------------------------------------------------------------------
__global__ __launch_bounds__(256) void k_alpha(const int* __restrict__ adj,
                                               const float* __restrict__ e_src,
                                               const float* __restrict__ e_dst,
                                               const float* __restrict__ mArr,
                                               const float* __restrict__ rlArr,
                                               float* __restrict__ alpha) {
    const int bi = blockIdx.x;
    const int b = bi / NN, i = bi - b * NN;
    const int t = threadIdx.x;
    float ei[HH], mm[HH], rr[HH];
#pragma unroll
    for (int h = 0; h < HH; ++h) {
        ei[h] = e_src[(b * HH + h) * NN + i];
        mm[h] = mArr[(b * HH + h) * NN + i];
        rr[h] = rlArr[(b * HH + h) * NN + i];
    }
    const float* ed = e_dst + b * HH * NN;
    const int* adjrow = adj + (size_t)i * NN;
    float* arow = alpha + (size_t)(b * NN + i) * (NN * HH);
    for (int jq = t; jq < NN / 4; jq += 256) {
        const int j0 = jq * 4;
        const int4 av4 = *(const int4*)(adjrow + j0);
        const int avs[4] = {av4.x, av4.y, av4.z, av4.w};
        float e4[HH * 4];
#pragma unroll
        for (int h = 0; h < HH; ++h) {
            const float4 v = *(const float4*)(ed + h * NN + j0);
            e4[h * 4 + 0] = v.x; e4[h * 4 + 1] = v.y; e4[h * 4 + 2] = v.z; e4[h * 4 + 3] = v.w;
        }
#pragma unroll
        for (int jj = 0; jj < 4; ++jj) {
            const bool av = avs[jj] != 0;
            float o[HH];
#pragma unroll
            for (int h = 0; h < HH; ++h) {
                float s = ei[h] + e4[h * 4 + jj];
                s = s > 0.f ? s : 0.2f * s;
                o[h] = av ? __expf(s - mm[h]) * rr[h] : 0.f;
            }
            float4 ov = {o[0], o[1], o[2], o[3]};
            *(float4*)(arow + (size_t)(j0 + jj) * HH) = ov;
        }
    }
}

// ---------------------------------------------------------------------------
// Launch.  Scratch lives at the start of the alpha output region — dead until
// k_alpha, which runs LAST and reads only input/ws arrays (no scratch!).
//   alpha region layout (floats from alpha base):
//     [0,        4096000)  hfeat
//     [4096000,  6193152)  hT   (bf16 fragment-order, [32 bh][64 s][2048])
//     [6193152,  +128000)  adjb (u64,  [2000][32])
// ---------------------------------------------------------------------------
extern "C" void kernel_launch(void* const* d_in, const int* in_sizes, int n_in,
                              void* d_out, int out_size, void* d_ws, size_t ws_size,
                              hipStream_t stream) {
    const float* x  = (const float*)d_in[0];
    const int* adj  = (const int*)d_in[1];
    const float* W  = (const float*)d_in[2];
    const float* a  = (const float*)d_in[3];

    float* out = (float*)d_out;                         // B*N*FO floats
    float* alpha = out + (size_t)BB * NN * FO;          // B*N*N*H floats

    float* hfeat = alpha;
    unsigned short* hT = (unsigned short*)(alpha + (size_t)BB * NN * CC);
    u64* adjb = (u64*)(alpha + (size_t)BB * NN * CC + (size_t)BB * HH * FO * 1024);

    float* ws    = (float*)d_ws;
    float* e_src = ws;
    float* e_dst = e_src + BB * HH * NN;
    float* mArr  = e_dst + BB * HH * NN;
    float* rlArr = mArr + BB * HH * NN;

    k_gemm_xw<<<1000, 256, 0, stream>>>(x, W, hfeat);
    k_adjbits<<<16000, 256, 0, stream>>>(adj, adjb);
    k_calc_e<<<16000, 256, 0, stream>>>(hfeat, a, e_src, e_dst);
    k_softmax_ml<<<16000, 256, 0, stream>>>(adjb, e_src, e_dst, mArr, rlArr);
    k_transpose<<<dim3(32, HH, BB), 256, 0, stream>>>(hfeat, hT);
    k_out_mfma3<<<1000, 256, 0, stream>>>(adjb, hT, e_src, e_dst, mArr, rlArr, out);
    k_alpha<<<16000, 256, 0, stream>>>(adj, e_src, e_dst, mArr, rlArr, alpha);  // overwrites scratch
}